// Round 1
// baseline (993.640 us; speedup 1.0000x reference)
//
#include <hip/hip_runtime.h>
#include <cstdint>
#include <cstddef>

#define H_   512
#define W_   1024
#define HP_  256
#define WP_  512
#define NTAP 9
#define CIN  128
#define COUT 64
#define HWP  (HP_*WP_)      /* 131072 */
#define MIDX (HWP*NTAP)     /* 1179648 */
#define HW_  (H_*W_)        /* 524288 */

typedef __attribute__((ext_vector_type(8))) short bhalf8_t;
typedef __attribute__((ext_vector_type(4))) float floatx4_t;

__device__ __forceinline__ unsigned short f2bf(float f) {
    unsigned u = __float_as_uint(f);
    u += 0x7fffu + ((u >> 16) & 1u);
    return (unsigned short)(u >> 16);
}
__device__ __forceinline__ float bf2f(unsigned short s) {
    return __uint_as_float(((unsigned)s) << 16);
}

// ---------------- K0: prep weights (permute+bf16) and zero stat accumulators ----------
__global__ __launch_bounds__(256) void k0_prep(
    const float* __restrict__ w_conv, const float* __restrict__ w_post,
    unsigned short* __restrict__ w2, unsigned short* __restrict__ wpostbf,
    float* __restrict__ gnzero /*256 floats: gnsum1+gnsum2*/) {
    int idx = blockIdx.x * 256 + threadIdx.x;
    if (idx < 576*128) {
        int r = idx >> 7, c = idx & 127;
        int o = r / 9, n = r % 9;                       // w_conv row r = o*9+n
        w2[((n*64 + o) << 7) + c] = f2bf(w_conv[idx]);  // w2 row = n*64+o
    } else if (idx < 576*128 + 4096) {
        int i2 = idx - 576*128;
        wpostbf[i2] = f2bf(w_post[i2]);
    } else if (idx < 576*128 + 4096 + 256) {
        gnzero[idx - (576*128 + 4096)] = 0.f;
    }
}

// ---------------- K1: GroupNorm1 partial stats (atomic accumulate per (b,g)) ----------
__global__ __launch_bounds__(256) void k1_stats(const float* __restrict__ x,
                                                float* __restrict__ gnsum1) {
    __shared__ float red[512];
    int bid = blockIdx.x;                 // 512 blocks: (b, g, slice)
    int b = bid >> 8, rem = bid & 255;
    int g = rem >> 3, slice = rem & 7;
    const float4* xp = (const float4*)x + (size_t)(b*CIN + g*4) * (HWP/4) + (size_t)slice*16384;
    float s = 0.f, s2 = 0.f;
    for (int i = threadIdx.x; i < 16384; i += 256) {
        float4 v = xp[i];
        s  += v.x + v.y + v.z + v.w;
        s2 += v.x*v.x + v.y*v.y + v.z*v.z + v.w*v.w;
    }
    red[threadIdx.x] = s; red[256 + threadIdx.x] = s2;
    __syncthreads();
    for (int off = 128; off > 0; off >>= 1) {
        if (threadIdx.x < off) {
            red[threadIdx.x] += red[threadIdx.x + off];
            red[256 + threadIdx.x] += red[256 + threadIdx.x + off];
        }
        __syncthreads();
    }
    if (threadIdx.x == 0) {
        atomicAdd(&gnsum1[(b*32 + g)*2],     red[0]);
        atomicAdd(&gnsum1[(b*32 + g)*2 + 1], red[256]);
    }
}

// ---------------- K1b: finalize GN1 -> per (b,c) affine coefficients -----------------
__global__ void k1b_coef(const float* __restrict__ gnsum1,
                         const float* __restrict__ gamma1, const float* __restrict__ beta1,
                         float* __restrict__ acoef, float* __restrict__ bcoef) {
    int t = threadIdx.x;                 // 256 = 2*128
    int b = t >> 7, c = t & 127, g = c >> 2;
    float s1 = gnsum1[(b*32+g)*2], s2 = gnsum1[(b*32+g)*2+1];
    const float inv = 1.f / 524288.f;
    float mean = s1 * inv;
    float var  = s2 * inv - mean*mean;
    float rstd = rsqrtf(var + 1e-5f);
    float a = gamma1[c] * rstd;
    acoef[t] = a;
    bcoef[t] = beta1[c] - mean * a;
}

// ---------------- K2: normalized 1x1 conv via MFMA -> vals[b][p][n][o] bf16 ----------
__global__ __launch_bounds__(256) void k2_conv(
    const float* __restrict__ x, const unsigned short* __restrict__ w2,
    const float* __restrict__ acoef, const float* __restrict__ bcoef,
    unsigned short* __restrict__ vals) {
    __shared__ unsigned short As[64*136];   // w2 tile [o][k], pad 8
    __shared__ unsigned short Bs[128*136];  // xnorm tile [p][k], pad 8
    __shared__ unsigned short Cs[128*72];   // out stage [p][o], pad 8
    int b   = blockIdx.y;
    int tile = blockIdx.x;                  // 1024: pr*4 + pc-quarter
    int pr  = tile >> 2, pcb = (tile & 3) << 7;
    int tid = threadIdx.x;

    // stage Bs: 128 p x 128 c, normalize on the fly, bf16, b128 LDS writes
    for (int task = tid; task < 2048; task += 256) {
        int p = task & 127, c0 = (task >> 7) << 3;
        bhalf8_t t8;
        #pragma unroll
        for (int j = 0; j < 8; ++j) {
            int c = c0 + j;
            float xv = x[(size_t)(b*CIN + c)*HWP + (size_t)pr*WP_ + pcb + p];
            float v = fmaf(xv, acoef[b*CIN + c], bcoef[b*CIN + c]);
            t8[j] = (short)f2bf(v);
        }
        *(bhalf8_t*)&Bs[p*136 + c0] = t8;
    }
    __syncthreads();

    int wave = tid >> 6, lane = tid & 63;
    int l15 = lane & 15, lq = lane >> 4;

    // hoist B fragments (identical across all 9 M-tiles)
    bhalf8_t bfr[2][4];
    #pragma unroll
    for (int ptl = 0; ptl < 2; ++ptl) {
        int p = (wave*2 + ptl)*16 + l15;
        #pragma unroll
        for (int ks = 0; ks < 4; ++ks)
            bfr[ptl][ks] = *(const bhalf8_t*)&Bs[p*136 + ks*32 + lq*8];
    }

    for (int n = 0; n < 9; ++n) {
        __syncthreads();
        for (int i = tid; i < 4096; i += 256) {          // stage As (uint copy)
            int r = i >> 6, cp = i & 63;
            ((unsigned*)As)[r*68 + cp] = ((const unsigned*)w2)[(n*64 + r)*64 + cp];
        }
        __syncthreads();
        floatx4_t acc[2][4] = {};
        #pragma unroll
        for (int ks = 0; ks < 4; ++ks) {
            bhalf8_t af[4];
            #pragma unroll
            for (int rt = 0; rt < 4; ++rt)
                af[rt] = *(const bhalf8_t*)&As[(rt*16 + l15)*136 + ks*32 + lq*8];
            #pragma unroll
            for (int ptl = 0; ptl < 2; ++ptl)
                #pragma unroll
                for (int rt = 0; rt < 4; ++rt)
                    acc[ptl][rt] = __builtin_amdgcn_mfma_f32_16x16x32_bf16(
                        af[rt], bfr[ptl][ks], acc[ptl][rt], 0, 0, 0);
        }
        // acc -> Cs  (D layout: col(lane&15)=p, row(quad*4+reg)=o)
        #pragma unroll
        for (int ptl = 0; ptl < 2; ++ptl) {
            int p = (wave*2 + ptl)*16 + l15;
            #pragma unroll
            for (int rt = 0; rt < 4; ++rt)
                #pragma unroll
                for (int reg = 0; reg < 4; ++reg) {
                    int o = rt*16 + lq*4 + reg;
                    Cs[p*72 + o] = f2bf(acc[ptl][rt][reg]);
                }
        }
        __syncthreads();
        size_t outbase = (size_t)b*HWP + (size_t)pr*WP_ + pcb;
        for (int i = tid; i < 4096; i += 256) {          // coalesced uint store
            int p = i >> 5, o2 = i & 31;
            ((unsigned*)vals)[((outbase + p)*576 + n*64)/2 + o2] = ((const unsigned*)Cs)[p*36 + o2];
        }
    }
}

// ---------------- K3: gather-splat + normalize + post 1x1 conv (MFMA) + GN2 stats ----
__global__ __launch_bounds__(256) void k3_gather(
    const float* __restrict__ gridp, const unsigned short* __restrict__ vals,
    const unsigned short* __restrict__ wpostbf,
    const float* __restrict__ splat_bias, const float* __restrict__ b_post,
    float* __restrict__ out, float* __restrict__ gnsum2) {

    __shared__ unsigned short SM[256*72];   // out1 [px][c] bf16, pad 8
    __shared__ unsigned short WPs[64*72];   // w_post [o][c] bf16, pad 8
    __shared__ float sb_s[64], bp_s[64], gsum[64];

    int tid = threadIdx.x;
    int bx = blockIdx.x;        // 0..3  (x-tile of 256)
    int y  = blockIdx.y;        // 0..511
    int b  = blockIdx.z;        // 0..1
    int x  = (bx << 8) + tid;

    if (tid < 64) { sb_s[tid] = splat_bias[tid]; bp_s[tid] = b_post[tid]; gsum[tid] = 0.f; }
    for (int i = tid; i < 2048; i += 256) {
        int r = i >> 5, cp = i & 31;
        ((unsigned*)WPs)[r*36 + cp] = ((const unsigned*)wpostbf)[(r << 5) + cp];
    }

    float num[64];
    #pragma unroll
    for (int c = 0; c < 64; ++c) num[c] = 0.f;
    float den = 0.f;

    const float2* g2 = (const float2*)gridp;
    int prc = y >> 1;
    for (int dpr = -1; dpr <= 1; ++dpr) {
        int pr = prc + dpr;
        if (pr < 0 || pr > HP_-1) continue;
        for (int kyi = 0; kyi < 3; ++kyi) {
            // row geometry (pc-invariant bitwise): read at pc=0, kx=0
            float gy = g2[pr*WP_*9 + kyi*3 + 1].y;
            float py = ((gy + 1.0f) * 0.5f) * 511.0f;
            float y0f = floorf(py);
            float fy = py - y0f;
            int y0i = (int)y0f;
            #pragma unroll
            for (int side = 0; side < 2; ++side) {
                int yi = y0i + side;
                bool pn = yi < 0, ps = yi >= H_;
                int yy = pn ? -yi : (ps ? (2*H_ - yi) : yi);
                yy = min(max(yy, 0), H_-1);
                if (yy != y) continue;
                int sh = (pn || ps) ? (W_/2) : 0;
                float wy = side ? fy : (1.0f - fy);
                for (int kxi = 0; kxi < 3; ++kxi) {
                    int n = kyi*3 + kxi;
                    float gx0 = g2[pr*WP_*9 + n].x;
                    float px0 = ((gx0 + 1.0f) * 0.5f) * 1023.0f;  // model: px(pc)=px0+2pc
                    int Tt = x - sh - 1;
                    #pragma unroll
                    for (int j = -1; j <= 1; ++j) {
                        float A = ((float)(Tt + j*W_) - px0) * 0.5f;
                        int clo = (int)ceilf(A - 1e-3f);
                        int chi = (int)floorf(A + 1.001f);
                        for (int pc = clo; pc <= chi; ++pc) {
                            if (pc < 0 || pc >= WP_) continue;
                            int m = (pr*WP_ + pc)*9 + n;
                            float2 g = g2[m];
                            float px = ((g.x + 1.0f) * 0.5f) * 1023.0f;  // exact ref arith
                            float x0f = floorf(px);
                            float fx = px - x0f;
                            int x0i = (int)x0f;
                            int xl = (x0i + 2*W_ + sh) & (W_-1);
                            float w;
                            if (xl == x)                      w = (1.0f - fx) * wy;
                            else if (((xl + 1) & (W_-1)) == x) w = fx * wy;
                            else continue;
                            den += w;
                            const uint4* vp = (const uint4*)(vals + (((size_t)b*MIDX + m) << 6));
                            #pragma unroll
                            for (int q = 0; q < 8; ++q) {
                                uint4 u = vp[q];
                                unsigned uu[4] = {u.x, u.y, u.z, u.w};
                                #pragma unroll
                                for (int e = 0; e < 4; ++e) {
                                    float lo = __uint_as_float(uu[e] << 16);
                                    float hi = __uint_as_float(uu[e] & 0xffff0000u);
                                    num[q*8 + e*2]     = fmaf(w, lo, num[q*8 + e*2]);
                                    num[q*8 + e*2 + 1] = fmaf(w, hi, num[q*8 + e*2 + 1]);
                                }
                            }
                        }
                    }
                }
            }
        }
    }

    // out1 = num/den + splat_bias -> LDS bf16 [px][c]
    float invd = 1.0f / fmaxf(den, 1e-8f);
    {
        int base = tid * 72;
        #pragma unroll
        for (int c8 = 0; c8 < 8; ++c8) {
            bhalf8_t t8;
            #pragma unroll
            for (int jj = 0; jj < 8; ++jj) {
                float v = fmaf(num[c8*8 + jj], invd, sb_s[c8*8 + jj]);
                t8[jj] = (short)f2bf(v);
            }
            *(bhalf8_t*)&SM[base + c8*8] = t8;
        }
    }
    __syncthreads();

    // post conv: D[o][px] = sum_c w_post[o][c] * out1[px][c]
    int wave = tid >> 6, lane = tid & 63, l15 = lane & 15, lq = lane >> 4;
    floatx4_t acc[4][4] = {};
    #pragma unroll
    for (int ks = 0; ks < 2; ++ks) {
        bhalf8_t af[4], bf[4];
        #pragma unroll
        for (int ot = 0; ot < 4; ++ot)
            af[ot] = *(const bhalf8_t*)&WPs[(ot*16 + l15)*72 + ks*32 + lq*8];
        #pragma unroll
        for (int pt = 0; pt < 4; ++pt)
            bf[pt] = *(const bhalf8_t*)&SM[((wave*4 + pt)*16 + l15)*72 + ks*32 + lq*8];
        #pragma unroll
        for (int pt = 0; pt < 4; ++pt)
            #pragma unroll
            for (int ot = 0; ot < 4; ++ot)
                acc[pt][ot] = __builtin_amdgcn_mfma_f32_16x16x32_bf16(
                    af[ot], bf[pt], acc[pt][ot], 0, 0, 0);
    }

    // epilogue: +b_post, store fp32 to out (pre-GN2, final layout), GN2 partial stats
    float s1l[8], s2l[8];
    #pragma unroll
    for (int li = 0; li < 8; ++li) { s1l[li] = 0.f; s2l[li] = 0.f; }
    #pragma unroll
    for (int pt = 0; pt < 4; ++pt) {
        int px = (wave*4 + pt)*16 + l15;
        int xg = (bx << 8) + px;
        #pragma unroll
        for (int ot = 0; ot < 4; ++ot)
            #pragma unroll
            for (int reg = 0; reg < 4; ++reg) {
                int o = ot*16 + lq*4 + reg;
                float v = acc[pt][ot][reg] + bp_s[o];
                out[((size_t)(b*64 + o) << 19) + ((size_t)y << 10) + xg] = v;
                int li = ot*2 + (reg >> 1);
                s1l[li] += v;
                s2l[li] += v*v;
            }
    }
    #pragma unroll
    for (int li = 0; li < 8; ++li) {
        int g = (li >> 1)*8 + lq*2 + (li & 1);   // g = o>>1 = ot*8 + lq*2 + (reg>>1)
        atomicAdd(&gsum[g*2],     s1l[li]);
        atomicAdd(&gsum[g*2 + 1], s2l[li]);
    }
    __syncthreads();
    if (tid < 64) atomicAdd(&gnsum2[b*64 + tid], gsum[tid]);
}

// ---------------- K5: in-place GroupNorm2 + exact GELU on d_out ----------------------
__global__ __launch_bounds__(256) void k5_final(
    float* __restrict__ out, const float* __restrict__ gnsum2,
    const float* __restrict__ gamma2, const float* __restrict__ beta2) {
    size_t idx = (size_t)blockIdx.x * 256 + threadIdx.x;   // 8388608 threads, 8 elems each
    size_t e8 = idx << 3;
    int b = (int)(e8 >> 25);
    int o = (int)((e8 >> 19) & 63);
    int g = o >> 1;
    float s1 = gnsum2[b*64 + g*2], s2 = gnsum2[b*64 + g*2 + 1];
    const float invn = 1.0f / 1048576.0f;
    float mean = s1 * invn;
    float var  = s2 * invn - mean*mean;
    float rstd = rsqrtf(var + 1e-5f);
    float sc = gamma2[o] * rstd;
    float sf = beta2[o] - mean * sc;
    float4* p0 = (float4*)(out + e8);
    float4 v0 = p0[0], v1 = p0[1];
    float r[8] = {v0.x, v0.y, v0.z, v0.w, v1.x, v1.y, v1.z, v1.w};
    #pragma unroll
    for (int j = 0; j < 8; ++j) {
        float t = fmaf(r[j], sc, sf);
        r[j] = 0.5f * t * (1.0f + erff(t * 0.70710678118654752f));
    }
    p0[0] = make_float4(r[0], r[1], r[2], r[3]);
    p0[1] = make_float4(r[4], r[5], r[6], r[7]);
}

// -------------------------------------------------------------------------------------
extern "C" void kernel_launch(void* const* d_in, const int* in_sizes, int n_in,
                              void* d_out, int out_size, void* d_ws, size_t ws_size,
                              hipStream_t stream) {
    const float* x      = (const float*)d_in[0];
    const float* gridp  = (const float*)d_in[1];
    const float* gamma1 = (const float*)d_in[2];
    const float* beta1  = (const float*)d_in[3];
    const float* w_conv = (const float*)d_in[4];
    const float* sbias  = (const float*)d_in[5];
    const float* w_post = (const float*)d_in[6];
    const float* b_post = (const float*)d_in[7];
    const float* gamma2 = (const float*)d_in[8];
    const float* beta2  = (const float*)d_in[9];
    float* out = (float*)d_out;

    char* ws = (char*)d_ws;
    unsigned short* w2      = (unsigned short*)(ws);                 // 147456 B
    unsigned short* wpostbf = (unsigned short*)(ws + 147456);        // 8192 B
    float* gnsum1 = (float*)(ws + 155648);                           // 512 B
    float* gnsum2 = (float*)(ws + 156160);                           // 512 B (contig w/ gnsum1)
    float* acoef  = (float*)(ws + 156672);                           // 1024 B
    float* bcoef  = (float*)(ws + 157696);                           // 1024 B
    unsigned short* vals = (unsigned short*)(ws + 158720);           // 301,989,888 B
    // total ws needed: 302,148,608 B (~288 MiB); out2 staged in d_out (fp32, in place)

    hipLaunchKernelGGL(k0_prep,  dim3(305),          dim3(256), 0, stream,
                       w_conv, w_post, w2, wpostbf, gnsum1);
    hipLaunchKernelGGL(k1_stats, dim3(512),          dim3(256), 0, stream, x, gnsum1);
    hipLaunchKernelGGL(k1b_coef, dim3(1),            dim3(256), 0, stream,
                       gnsum1, gamma1, beta1, acoef, bcoef);
    hipLaunchKernelGGL(k2_conv,  dim3(1024, 2),      dim3(256), 0, stream,
                       x, w2, acoef, bcoef, vals);
    hipLaunchKernelGGL(k3_gather, dim3(4, 512, 2),   dim3(256), 0, stream,
                       gridp, vals, wpostbf, sbias, b_post, out, gnsum2);
    hipLaunchKernelGGL(k5_final, dim3(32768),        dim3(256), 0, stream,
                       out, gnsum2, gamma2, beta2);
}